// Round 5
// baseline (826.649 us; speedup 1.0000x reference)
//
#include <hip/hip_runtime.h>

typedef __attribute__((ext_vector_type(8))) short frag_ab;   // 8 bf16 = 4 VGPRs
typedef __attribute__((ext_vector_type(4))) float frag_cd;   // 4 fp32 acc
typedef __attribute__((ext_vector_type(4))) short short4v;

__device__ __forceinline__ short f2bf(float f) {
  union { float f; unsigned u; } v; v.f = f;
  unsigned r = v.u + 0x7fffu + ((v.u >> 16) & 1u);   // RNE
  return (short)(r >> 16);
}

// ---------------------------------------------------------------------------
// wconv: convert fp32 weights [nmat][Keff][64] into MFMA B-fragment-ordered
// bf16: frag (s*4+ct), lane ln, element j = W[k=s*32+(ln>>4)*8+j][n=ct*16+(ln&15)]
// (zero-padded k >= Keff). Run ONCE; GEMMs then load B frags as single 16B
// global loads — no LDS staging for B.
// ---------------------------------------------------------------------------
__global__ void wconv(const float* __restrict__ W, short* __restrict__ out,
                      int Keff, int S, int nmat)
{
  int tid = blockIdx.x * 256 + threadIdx.x;
  int per = S * 4 * 64;
  if (tid >= nmat * per) return;
  int m = tid / per, r = tid % per;
  int s = r / 256, ct = (r >> 6) & 3, ln = r & 63;
  const float* Wm = W + (size_t)m * Keff * 64;
  __align__(16) short tmp[8];
  for (int j = 0; j < 8; ++j) {
    int k = s * 32 + (ln >> 4) * 8 + j;
    int n = ct * 16 + (ln & 15);
    tmp[j] = (k < Keff) ? f2bf(Wm[k * 64 + n]) : (short)0;
  }
  *(uint4*)&out[((size_t)m * per + (size_t)(s * 4 + ct) * 64 + ln) * 8] = *(uint4*)tmp;
}

// ---------------------------------------------------------------------------
// proj: hbf = bf16(x @ pw + pb).  A=[128][K=75 pad 96] bf16 in LDS; B frags
// from pre-converted wt (global, L2-resident).
// ---------------------------------------------------------------------------
#define AS1 104   // LDS row stride (bf16); 208 B = 13*16, 16B-aligned chunks
__global__ __launch_bounds__(256, 4) void proj_kernel(
    const float* __restrict__ x, const short* __restrict__ wt,
    const float* __restrict__ bias, short* __restrict__ hbf, int N)
{
  __shared__ __align__(16) short A[128 * AS1];
  int t = threadIdx.x;
  int nb = blockIdx.x * 128;
  int ln = t & 63;
  frag_ab bf[12];
  for (int s = 0; s < 3; ++s)
    for (int ct = 0; ct < 4; ++ct)
      bf[s * 4 + ct] = *(const frag_ab*)&wt[((size_t)(s * 4 + ct) * 64 + ln) * 8];
  for (int i = 0; i < 48; ++i) {                 // 128*96/256
    int q = i * 256 + t; int el = q / 96; int c = q - el * 96;
    int rg = nb + el;
    float v = (c < 75 && rg < N) ? x[rg * 75 + c] : 0.f;
    A[el * AS1 + c] = f2bf(v);
  }
  __syncthreads();
  int wv = t >> 6;
  int lrow = ln & 15, lk = ln >> 4;
  frag_cd acc[2][4];
  for (int rt = 0; rt < 2; ++rt) for (int ct = 0; ct < 4; ++ct) {
    frag_cd z = {0.f, 0.f, 0.f, 0.f}; acc[rt][ct] = z;
  }
  for (int s = 0; s < 3; ++s) {
    frag_ab a0 = *(const frag_ab*)&A[(wv*32 + lrow) * AS1 + s*32 + lk*8];
    frag_ab a1 = *(const frag_ab*)&A[(wv*32 + 16 + lrow) * AS1 + s*32 + lk*8];
    for (int ct = 0; ct < 4; ++ct) {
      acc[0][ct] = __builtin_amdgcn_mfma_f32_16x16x32_bf16(a0, bf[s*4+ct], acc[0][ct], 0, 0, 0);
      acc[1][ct] = __builtin_amdgcn_mfma_f32_16x16x32_bf16(a1, bf[s*4+ct], acc[1][ct], 0, 0, 0);
    }
  }
  float bv[4];
  for (int ct = 0; ct < 4; ++ct) bv[ct] = bias[ct*16 + lrow];
  for (int rt = 0; rt < 2; ++rt)
    for (int ct = 0; ct < 4; ++ct)
      for (int r = 0; r < 4; ++r) {
        int row = wv*32 + rt*16 + lk*4 + r;
        int rg = nb + row;
        if (rg < N) hbf[(size_t)rg * 64 + ct*16 + lrow] = f2bf(acc[rt][ct][r] + bv[ct]);
      }
}

// ---------------------------------------------------------------------------
// Counting sort of edges by dst: hist -> scan -> perm-scatter (4B payload only)
// -> gather-permute (coalesced big writes) with fused mask computation.
// ---------------------------------------------------------------------------
__global__ __launch_bounds__(256) void hist_kernel(
    const int* __restrict__ dst, int* __restrict__ counts, int E)
{
  int i = blockIdx.x * 256 + threadIdx.x;
  if (i < E) atomicAdd(&counts[dst[i]], 1);
}

#define SCAN_TILE 2048
__global__ __launch_bounds__(256) void scan_k1(
    const int* __restrict__ counts, int* __restrict__ offsets,
    int* __restrict__ bsum, int n)
{
  __shared__ int ts[256];
  int t = threadIdx.x;
  int base = blockIdx.x * SCAN_TILE + t * 8;
  int v[8]; int s = 0;
  for (int j = 0; j < 8; ++j) { v[j] = (base + j < n) ? counts[base + j] : 0; s += v[j]; }
  ts[t] = s; __syncthreads();
  for (int off = 1; off < 256; off <<= 1) {
    int x = (t >= off) ? ts[t - off] : 0;
    __syncthreads();
    ts[t] += x;
    __syncthreads();
  }
  if (t == 255) bsum[blockIdx.x] = ts[255];
  int run = (t > 0) ? ts[t - 1] : 0;
  for (int j = 0; j < 8; ++j) { if (base + j < n) offsets[base + j] = run; run += v[j]; }
}

__global__ void scan_k2(int* bsum, int nb) {
  if (threadIdx.x == 0 && blockIdx.x == 0) {
    int run = 0;
    for (int b = 0; b < nb; ++b) { int x = bsum[b]; bsum[b] = run; run += x; }
  }
}

__global__ __launch_bounds__(256) void scan_k3(
    int* __restrict__ offsets, const int* __restrict__ bsum, int n)
{
  int add = bsum[blockIdx.x];
  int base = blockIdx.x * SCAN_TILE + threadIdx.x;
  for (int j = 0; j < 8; ++j) { int i = base + j * 256; if (i < n) offsets[i] += add; }
}

// phase 1: minimal scattered payload — perm[p] = e (4 B)
__global__ __launch_bounds__(256) void perm_scatter(
    const int* __restrict__ dst, int* __restrict__ offsets,
    int* __restrict__ perm, int E)
{
  int e = blockIdx.x * 256 + threadIdx.x;
  if (e < E) {
    int p = atomicAdd(&offsets[dst[e]], 1);
    perm[p] = e;
  }
}

// phase 2: iterate sorted positions; random READS, coalesced WRITES.
// Fused mask build: per 32-row window, em bit i = row i ends its dst-run;
// cm = em minus (lowest set bit) minus bit31 (those runs may span windows).
__global__ __launch_bounds__(256) void gather_permute(
    const int* __restrict__ perm, const int* __restrict__ src,
    const int* __restrict__ dst, const float* __restrict__ attr,
    int* __restrict__ srcs, int* __restrict__ dsts,
    short* __restrict__ attr_s, uint2* __restrict__ masks, int E, int NW)
{
  int p = blockIdx.x * 256 + threadIdx.x;
  int d = -1;
  if (p < E) {
    int e = perm[p];
    d = dst[e];
    srcs[p] = src[e];
    dsts[p] = d;
    const float4* a4 = (const float4*)(attr + (size_t)e * 16);
    float4 v0 = a4[0], v1 = a4[1], v2 = a4[2], v3 = a4[3];
    __align__(16) short tmp[16];
    tmp[0]=f2bf(v0.x); tmp[1]=f2bf(v0.y); tmp[2]=f2bf(v0.z); tmp[3]=f2bf(v0.w);
    tmp[4]=f2bf(v1.x); tmp[5]=f2bf(v1.y); tmp[6]=f2bf(v1.z); tmp[7]=f2bf(v1.w);
    tmp[8]=f2bf(v2.x); tmp[9]=f2bf(v2.y); tmp[10]=f2bf(v2.z); tmp[11]=f2bf(v2.w);
    tmp[12]=f2bf(v3.x); tmp[13]=f2bf(v3.y); tmp[14]=f2bf(v3.z); tmp[15]=f2bf(v3.w);
    *(uint4*)&attr_s[(size_t)p * 16]     = *(uint4*)&tmp[0];
    *(uint4*)&attr_s[(size_t)p * 16 + 8] = *(uint4*)&tmp[8];
  }
  // wave = 2 windows of 32. Run-end if next row differs or window boundary.
  int dnext = __shfl_down(d, 1);
  bool end = ((p & 31) == 31) || (d != dnext);
  unsigned long long bm = __ballot(end);
  int lw = threadIdx.x & 63;
  if (lw == 0 || lw == 32) {
    unsigned em = (lw == 0) ? (unsigned)bm : (unsigned)(bm >> 32);
    unsigned cm = em & ~(em & (~em + 1u)) & 0x7fffffffu;
    int w = p >> 5;
    if (w < NW) masks[w] = make_uint2(em, cm);
  }
}

// ---------------------------------------------------------------------------
// msg: edges pre-sorted by dst. z=[hbf[src] | attr_s] (K=80 pad 96),
// m=leaky(z@W+b) via MFMA (B frags from global), m -> LDS M, then unrolled
// mask-driven segmented reduction. agg MUST be zeroed before launch (boundary
// runs accumulate via atomics).
// ---------------------------------------------------------------------------
#define MS 66
__global__ __launch_bounds__(256, 4) void msg_kernel(
    const short* __restrict__ hbf, const short* __restrict__ attr_s,
    const int* __restrict__ srcs, const int* __restrict__ dsts,
    const short* __restrict__ wt, const float* __restrict__ bias,
    const uint2* __restrict__ masks, float* __restrict__ agg, int E)
{
  __shared__ __align__(16) char u[128 * MS * 4];   // M(33792B) aliases A(26624B)
  __shared__ int dstl[128];
  short* A = (short*)u;
  float* M = (float*)u;

  int t = threadIdx.x;
  int eb = blockIdx.x * 128;
  int ln = t & 63;

  if (t < 128) dstl[t] = (eb + t < E) ? dsts[eb + t] : -1;

  frag_ab bf[12];
  for (int s = 0; s < 3; ++s)
    for (int ct = 0; ct < 4; ++ct)
      bf[s * 4 + ct] = *(const frag_ab*)&wt[((size_t)(s * 4 + ct) * 64 + ln) * 8];

  // h part: gather 16B chunks of hbf[srcs[p]]
  for (int i = 0; i < 4; ++i) {                  // 128*8/256
    int q = i * 256 + t; int el = q >> 3; int c = q & 7;
    int p = eb + el;
    int s = (p < E) ? srcs[p] : 0;
    *(uint4*)&A[el * AS1 + c * 8] = *(const uint4*)&hbf[(size_t)s * 64 + c * 8];
  }
  // attr part: coalesced bf16 stream, 1 chunk/thread; then zero pad k=80..95
  {
    int el = t >> 1, c = t & 1;
    int p = eb + el;
    uint4 v = {0u, 0u, 0u, 0u};
    if (p < E) v = *(const uint4*)&attr_s[(size_t)p * 16 + c * 8];
    *(uint4*)&A[el * AS1 + 64 + c * 8] = v;
    uint4 z = {0u, 0u, 0u, 0u};
    *(uint4*)&A[el * AS1 + 80 + c * 8] = z;
  }
  __syncthreads();

  int wv = t >> 6;
  int lrow = ln & 15, lk = ln >> 4;
  frag_cd acc[2][4];
  for (int rt = 0; rt < 2; ++rt) for (int ct = 0; ct < 4; ++ct) {
    frag_cd z = {0.f, 0.f, 0.f, 0.f}; acc[rt][ct] = z;
  }
  for (int s = 0; s < 3; ++s) {
    frag_ab a0 = *(const frag_ab*)&A[(wv*32 + lrow) * AS1 + s*32 + lk*8];
    frag_ab a1 = *(const frag_ab*)&A[(wv*32 + 16 + lrow) * AS1 + s*32 + lk*8];
    for (int ct = 0; ct < 4; ++ct) {
      acc[0][ct] = __builtin_amdgcn_mfma_f32_16x16x32_bf16(a0, bf[s*4+ct], acc[0][ct], 0, 0, 0);
      acc[1][ct] = __builtin_amdgcn_mfma_f32_16x16x32_bf16(a1, bf[s*4+ct], acc[1][ct], 0, 0, 0);
    }
  }
  float bv[4];
  for (int ct = 0; ct < 4; ++ct) bv[ct] = bias[ct*16 + lrow];

  __syncthreads();   // A dead; M aliases it
  for (int rt = 0; rt < 2; ++rt)
    for (int ct = 0; ct < 4; ++ct)
      for (int r = 0; r < 4; ++r) {
        int row = wv*32 + rt*16 + lk*4 + r;
        float m = acc[rt][ct][r] + bv[ct];
        m = m > 0.f ? m : 0.1f * m;              // LeakyReLU(0.1)
        M[row * MS + ct*16 + lrow] = m;
      }
  __syncthreads();

  // unrolled segmented reduction: wave wv owns rows [wv*32, wv*32+32),
  // lane ln owns column ln; masks are wave-uniform scalars.
  {
    uint2 mk = masks[blockIdx.x * 4 + wv];
    unsigned em = __builtin_amdgcn_readfirstlane(mk.x);
    unsigned cm = __builtin_amdgcn_readfirstlane(mk.y);
    float s = 0.f;
#pragma unroll
    for (int i = 0; i < 32; ++i) {
      s += M[(wv*32 + i) * MS + ln];
      if ((em >> i) & 1u) {
        int d = __builtin_amdgcn_readfirstlane(dstl[wv*32 + i]);
        if (d >= 0) {
          float* dest = &agg[(size_t)d * 64 + ln];
          if ((cm >> i) & 1u) *dest = s;
          else unsafeAtomicAdd(dest, s);
        }
        s = 0.f;
      }
    }
  }
}

// ---------------------------------------------------------------------------
// update: h = [hbf | agg] @ u1_w + b.  K=128 exact. B frags from global.
// Zeroes agg rows after staging (next layer's msg needs zeroed base) — each
// row is touched by exactly one thread of one block, so plain stores race-free.
// fp32 output written only on last layer.
// ---------------------------------------------------------------------------
#define AS2 136   // 272 B row stride, 16B-aligned chunks
__global__ __launch_bounds__(256, 4) void upd_kernel(
    const short* __restrict__ hbf, float* __restrict__ agg,
    const short* __restrict__ wt, const float* __restrict__ bias,
    float* __restrict__ hout, short* __restrict__ hbfo, int N, int last)
{
  __shared__ __align__(16) short A[128 * AS2];
  int t = threadIdx.x;
  int nb = blockIdx.x * 128;
  int ln = t & 63;
  for (int i = 0; i < 4; ++i) {                  // h half (bf16 copy)
    int q = i * 256 + t; int el = q >> 3; int c = q & 7;
    int rg = nb + el;
    uint4 v = {0u, 0u, 0u, 0u};
    if (rg < N) v = *(const uint4*)&hbf[(size_t)rg * 64 + c * 8];
    *(uint4*)&A[el * AS2 + c * 8] = v;
  }
  for (int i = 0; i < 8; ++i) {                  // agg half fp32->bf16 (+zero)
    int q = i * 256 + t; int el = q >> 4; int c = q & 15;
    int rg = nb + el;
    float4 v = make_float4(0.f, 0.f, 0.f, 0.f);
    if (rg < N) {
      v = *(const float4*)&agg[(size_t)rg * 64 + c * 4];
      if (!last) {
        float4 z = make_float4(0.f, 0.f, 0.f, 0.f);
        *(float4*)&agg[(size_t)rg * 64 + c * 4] = z;
      }
    }
    short4v s4 = { f2bf(v.x), f2bf(v.y), f2bf(v.z), f2bf(v.w) };
    *(short4v*)&A[el * AS2 + 64 + c * 4] = s4;
  }
  __syncthreads();
  int wv = t >> 6;
  int lrow = ln & 15, lk = ln >> 4;
  frag_cd acc[2][4];
  for (int rt = 0; rt < 2; ++rt) for (int ct = 0; ct < 4; ++ct) {
    frag_cd z = {0.f, 0.f, 0.f, 0.f}; acc[rt][ct] = z;
  }
  for (int s = 0; s < 4; ++s) {
    frag_ab a0 = *(const frag_ab*)&A[(wv*32 + lrow) * AS2 + s*32 + lk*8];
    frag_ab a1 = *(const frag_ab*)&A[(wv*32 + 16 + lrow) * AS2 + s*32 + lk*8];
    for (int ct = 0; ct < 4; ++ct) {
      frag_ab b = *(const frag_ab*)&wt[((size_t)(s * 4 + ct) * 64 + ln) * 8];
      acc[0][ct] = __builtin_amdgcn_mfma_f32_16x16x32_bf16(a0, b, acc[0][ct], 0, 0, 0);
      acc[1][ct] = __builtin_amdgcn_mfma_f32_16x16x32_bf16(a1, b, acc[1][ct], 0, 0, 0);
    }
  }
  float bv[4];
  for (int ct = 0; ct < 4; ++ct) bv[ct] = bias[ct*16 + lrow];
  for (int rt = 0; rt < 2; ++rt)
    for (int ct = 0; ct < 4; ++ct)
      for (int r = 0; r < 4; ++r) {
        int row = wv*32 + rt*16 + lk*4 + r;
        int rg = nb + row;
        if (rg < N) {
          float v = acc[rt][ct][r] + bv[ct];
          if (last) hout[(size_t)rg * 64 + ct*16 + lrow] = v;
          hbfo[(size_t)rg * 64 + ct*16 + lrow] = f2bf(v);
        }
      }
}

extern "C" void kernel_launch(void* const* d_in, const int* in_sizes, int n_in,
                              void* d_out, int out_size, void* d_ws, size_t ws_size,
                              hipStream_t stream) {
  const float* x    = (const float*)d_in[0];
  const int*   ei   = (const int*)d_in[1];
  const float* attr = (const float*)d_in[2];
  const float* pw   = (const float*)d_in[3];
  const float* pb   = (const float*)d_in[4];
  const float* u2w  = (const float*)d_in[5];
  const float* u2b  = (const float*)d_in[6];
  const float* u1w  = (const float*)d_in[7];
  const float* u1b  = (const float*)d_in[8];

  const int N = in_sizes[0] / 75;
  const int E = in_sizes[1] / 2;
  const int* src = ei;
  const int* dst = ei + E;

  float* hout = (float*)d_out;
  char*  ws   = (char*)d_ws;
  size_t nh   = (size_t)N * 64;
  size_t off  = 0;
  short* hbf   = (short*)(ws + off); off += nh * 2;              // 12.8 MB
  float* agg   = (float*)(ws + off); off += nh * 4;              // 25.6 MB
  int*   srcs  = (int*)  (ws + off); off += (size_t)E * 4;       //  6.4 MB
  int*   dsts  = (int*)  (ws + off); off += (size_t)E * 4;       //  6.4 MB
  int*   perm  = (int*)  (ws + off); off += (size_t)E * 4;       //  6.4 MB
  short* attr_s= (short*)(ws + off); off += (size_t)E * 32;      // 51.2 MB
  const int EB = (E + 127) / 128;
  uint2* masks = (uint2*)(ws + off); off += (size_t)EB * 4 * 8;  //  0.4 MB
  short* projt = (short*)(ws + off); off += 3 * 4 * 64 * 8 * 2;
  short* u2t   = (short*)(ws + off); off += (size_t)3 * 3 * 4 * 64 * 8 * 2;
  short* u1t   = (short*)(ws + off); off += (size_t)3 * 4 * 4 * 64 * 8 * 2;
  // sort scratch overlays agg (dead until msg):
  int* counts  = (int*)agg;
  int* offsets = counts + N;
  int* bsum    = offsets + N;

  const int NB = (N + 127) / 128;
  const int GE = (E + 255) / 256;
  const int NS = (N + SCAN_TILE - 1) / SCAN_TILE;
  const int NW = EB * 4;
  const int GP = (NW * 32 + 255) / 256;

  // one-time preprocessing
  wconv<<<3, 256, 0, stream>>>(pw, projt, 75, 3, 1);
  wconv<<<9, 256, 0, stream>>>(u2w, u2t, 80, 3, 3);
  wconv<<<12, 256, 0, stream>>>(u1w, u1t, 128, 4, 3);
  proj_kernel<<<NB, 256, 0, stream>>>(x, projt, pb, hbf, N);
  hipMemsetAsync(counts, 0, (size_t)N * 4, stream);
  hist_kernel<<<GE, 256, 0, stream>>>(dst, counts, E);
  scan_k1<<<NS, 256, 0, stream>>>(counts, offsets, bsum, N);
  scan_k2<<<1, 64, 0, stream>>>(bsum, NS);
  scan_k3<<<NS, 256, 0, stream>>>(offsets, bsum, N);
  perm_scatter<<<GE, 256, 0, stream>>>(dst, offsets, perm, E);
  gather_permute<<<GP, 256, 0, stream>>>(perm, src, dst, attr,
                                         srcs, dsts, attr_s, masks, E, NW);

  hipMemsetAsync(agg, 0, nh * 4, stream);       // layer 0 base; upd re-zeros after
  for (int l = 0; l < 3; ++l) {
    msg_kernel<<<EB, 256, 0, stream>>>(hbf, attr_s, srcs, dsts,
                                       u2t + (size_t)l * 6144, u2b + l * 64,
                                       masks, agg, E);
    upd_kernel<<<NB, 256, 0, stream>>>(hbf, agg,
                                       u1t + (size_t)l * 8192, u1b + l * 64,
                                       hout, hbf, N, l == 2);
  }
}

// Round 6
// 703.313 us; speedup vs baseline: 1.1754x; 1.1754x over previous
//
#include <hip/hip_runtime.h>

typedef __attribute__((ext_vector_type(8))) short frag_ab;   // 8 bf16 = 4 VGPRs
typedef __attribute__((ext_vector_type(4))) float frag_cd;   // 4 fp32 acc
typedef __attribute__((ext_vector_type(4))) short short4v;

__device__ __forceinline__ short f2bf(float f) {
  union { float f; unsigned u; } v; v.f = f;
  unsigned r = v.u + 0x7fffu + ((v.u >> 16) & 1u);   // RNE
  return (short)(r >> 16);
}

// ---------------------------------------------------------------------------
// wconv: convert fp32 weights [nmat][Keff][64] into MFMA B-fragment-ordered
// bf16: frag (s*4+ct), lane ln, element j = W[k=s*32+(ln>>4)*8+j][n=ct*16+(ln&15)]
// (zero-padded k >= Keff). Run ONCE; GEMMs then load B frags as single 16B
// global loads — no LDS staging for B.
// ---------------------------------------------------------------------------
__global__ void wconv(const float* __restrict__ W, short* __restrict__ out,
                      int Keff, int S, int nmat)
{
  int tid = blockIdx.x * 256 + threadIdx.x;
  int per = S * 4 * 64;
  if (tid >= nmat * per) return;
  int m = tid / per, r = tid % per;
  int s = r / 256, ct = (r >> 6) & 3, ln = r & 63;
  const float* Wm = W + (size_t)m * Keff * 64;
  __align__(16) short tmp[8];
  for (int j = 0; j < 8; ++j) {
    int k = s * 32 + (ln >> 4) * 8 + j;
    int n = ct * 16 + (ln & 15);
    tmp[j] = (k < Keff) ? f2bf(Wm[k * 64 + n]) : (short)0;
  }
  *(uint4*)&out[((size_t)m * per + (size_t)(s * 4 + ct) * 64 + ln) * 8] = *(uint4*)tmp;
}

// ---------------------------------------------------------------------------
// proj: hbf = bf16(x @ pw + pb).  A=[128][K=75 pad 96] bf16 in LDS; B frags
// from pre-converted wt (global, L2-resident).
// ---------------------------------------------------------------------------
#define AS1 104   // LDS row stride (bf16); 208 B = 13*16, 16B-aligned chunks
__global__ __launch_bounds__(256, 4) void proj_kernel(
    const float* __restrict__ x, const short* __restrict__ wt,
    const float* __restrict__ bias, short* __restrict__ hbf, int N)
{
  __shared__ __align__(16) short A[128 * AS1];
  int t = threadIdx.x;
  int nb = blockIdx.x * 128;
  int ln = t & 63;
  frag_ab bf[12];
  for (int s = 0; s < 3; ++s)
    for (int ct = 0; ct < 4; ++ct)
      bf[s * 4 + ct] = *(const frag_ab*)&wt[((size_t)(s * 4 + ct) * 64 + ln) * 8];
  for (int i = 0; i < 48; ++i) {                 // 128*96/256
    int q = i * 256 + t; int el = q / 96; int c = q - el * 96;
    int rg = nb + el;
    float v = (c < 75 && rg < N) ? x[rg * 75 + c] : 0.f;
    A[el * AS1 + c] = f2bf(v);
  }
  __syncthreads();
  int wv = t >> 6;
  int lrow = ln & 15, lk = ln >> 4;
  frag_cd acc[2][4];
  for (int rt = 0; rt < 2; ++rt) for (int ct = 0; ct < 4; ++ct) {
    frag_cd z = {0.f, 0.f, 0.f, 0.f}; acc[rt][ct] = z;
  }
  for (int s = 0; s < 3; ++s) {
    frag_ab a0 = *(const frag_ab*)&A[(wv*32 + lrow) * AS1 + s*32 + lk*8];
    frag_ab a1 = *(const frag_ab*)&A[(wv*32 + 16 + lrow) * AS1 + s*32 + lk*8];
    for (int ct = 0; ct < 4; ++ct) {
      acc[0][ct] = __builtin_amdgcn_mfma_f32_16x16x32_bf16(a0, bf[s*4+ct], acc[0][ct], 0, 0, 0);
      acc[1][ct] = __builtin_amdgcn_mfma_f32_16x16x32_bf16(a1, bf[s*4+ct], acc[1][ct], 0, 0, 0);
    }
  }
  float bv[4];
  for (int ct = 0; ct < 4; ++ct) bv[ct] = bias[ct*16 + lrow];
  for (int rt = 0; rt < 2; ++rt)
    for (int ct = 0; ct < 4; ++ct)
      for (int r = 0; r < 4; ++r) {
        int row = wv*32 + rt*16 + lk*4 + r;
        int rg = nb + row;
        if (rg < N) hbf[(size_t)rg * 64 + ct*16 + lrow] = f2bf(acc[rt][ct][r] + bv[ct]);
      }
}

// ---------------------------------------------------------------------------
// Counting sort of edges by dst: hist -> scan -> fused scatter (sd int2 +
// attr bf16 permute in one pass; 3 scattered transactions per edge).
// ---------------------------------------------------------------------------
__global__ __launch_bounds__(256) void hist_kernel(
    const int* __restrict__ dst, int* __restrict__ counts, int E)
{
  int i = blockIdx.x * 256 + threadIdx.x;
  if (i < E) atomicAdd(&counts[dst[i]], 1);
}

#define SCAN_TILE 2048
__global__ __launch_bounds__(256) void scan_k1(
    const int* __restrict__ counts, int* __restrict__ offsets,
    int* __restrict__ bsum, int n)
{
  __shared__ int ts[256];
  int t = threadIdx.x;
  int base = blockIdx.x * SCAN_TILE + t * 8;
  int v[8]; int s = 0;
  for (int j = 0; j < 8; ++j) { v[j] = (base + j < n) ? counts[base + j] : 0; s += v[j]; }
  ts[t] = s; __syncthreads();
  for (int off = 1; off < 256; off <<= 1) {
    int x = (t >= off) ? ts[t - off] : 0;
    __syncthreads();
    ts[t] += x;
    __syncthreads();
  }
  if (t == 255) bsum[blockIdx.x] = ts[255];
  int run = (t > 0) ? ts[t - 1] : 0;
  for (int j = 0; j < 8; ++j) { if (base + j < n) offsets[base + j] = run; run += v[j]; }
}

__global__ void scan_k2(int* bsum, int nb) {
  if (threadIdx.x == 0 && blockIdx.x == 0) {
    int run = 0;
    for (int b = 0; b < nb; ++b) { int x = bsum[b]; bsum[b] = run; run += x; }
  }
}

__global__ __launch_bounds__(256) void scan_k3(
    int* __restrict__ offsets, const int* __restrict__ bsum, int n)
{
  int add = bsum[blockIdx.x];
  int base = blockIdx.x * SCAN_TILE + threadIdx.x;
  for (int j = 0; j < 8; ++j) { int i = base + j * 256; if (i < n) offsets[i] += add; }
}

__global__ __launch_bounds__(256) void scatter_kernel(
    const int* __restrict__ src, const int* __restrict__ dst,
    const float* __restrict__ attr, int* __restrict__ offsets,
    int2* __restrict__ sd, short* __restrict__ attr_s, int E)
{
  int e = blockIdx.x * 256 + threadIdx.x;
  if (e < E) {
    int d = dst[e];
    int p = atomicAdd(&offsets[d], 1);
    sd[p] = make_int2(src[e], d);
    const float4* a4 = (const float4*)(attr + (size_t)e * 16);
    float4 v0 = a4[0], v1 = a4[1], v2 = a4[2], v3 = a4[3];
    __align__(16) short tmp[16];
    tmp[0]=f2bf(v0.x); tmp[1]=f2bf(v0.y); tmp[2]=f2bf(v0.z); tmp[3]=f2bf(v0.w);
    tmp[4]=f2bf(v1.x); tmp[5]=f2bf(v1.y); tmp[6]=f2bf(v1.z); tmp[7]=f2bf(v1.w);
    tmp[8]=f2bf(v2.x); tmp[9]=f2bf(v2.y); tmp[10]=f2bf(v2.z); tmp[11]=f2bf(v2.w);
    tmp[12]=f2bf(v3.x); tmp[13]=f2bf(v3.y); tmp[14]=f2bf(v3.z); tmp[15]=f2bf(v3.w);
    *(uint4*)&attr_s[(size_t)p * 16]     = *(uint4*)&tmp[0];
    *(uint4*)&attr_s[(size_t)p * 16 + 8] = *(uint4*)&tmp[8];
  }
}

// ---------------------------------------------------------------------------
// msg: edges pre-sorted by dst. z=[hbf[sd.x] | attr_s] (K=80 pad 96),
// m=leaky(z@W+b) via MFMA (B frags from global), m -> LDS M, then unrolled
// mask-driven segmented reduction. Segment masks computed in-kernel via wave
// ballot over dstl. agg must be zeroed before launch (boundary atomics).
// ---------------------------------------------------------------------------
#define MS 66
__global__ __launch_bounds__(256, 4) void msg_kernel(
    const short* __restrict__ hbf, const short* __restrict__ attr_s,
    const int2* __restrict__ sd, const short* __restrict__ wt,
    const float* __restrict__ bias, float* __restrict__ agg, int E)
{
  __shared__ __align__(16) char u[128 * MS * 4];   // M(33792B) aliases A(26624B)
  __shared__ int dstl[128];
  short* A = (short*)u;
  float* M = (float*)u;

  int t = threadIdx.x;
  int eb = blockIdx.x * 128;
  int ln = t & 63;

  if (t < 128) dstl[t] = (eb + t < E) ? sd[eb + t].y : -1;

  frag_ab bf[12];
  for (int s = 0; s < 3; ++s)
    for (int ct = 0; ct < 4; ++ct)
      bf[s * 4 + ct] = *(const frag_ab*)&wt[((size_t)(s * 4 + ct) * 64 + ln) * 8];

  // h part: gather 16B chunks of hbf[sd[p].x]
  for (int i = 0; i < 4; ++i) {                  // 128*8/256
    int q = i * 256 + t; int el = q >> 3; int c = q & 7;
    int p = eb + el;
    int s = (p < E) ? sd[p].x : 0;
    *(uint4*)&A[el * AS1 + c * 8] = *(const uint4*)&hbf[(size_t)s * 64 + c * 8];
  }
  // attr part: coalesced bf16 stream, 1 chunk/thread; then zero pad k=80..95
  {
    int el = t >> 1, c = t & 1;
    int p = eb + el;
    uint4 v = {0u, 0u, 0u, 0u};
    if (p < E) v = *(const uint4*)&attr_s[(size_t)p * 16 + c * 8];
    *(uint4*)&A[el * AS1 + 64 + c * 8] = v;
    uint4 z = {0u, 0u, 0u, 0u};
    *(uint4*)&A[el * AS1 + 80 + c * 8] = z;
  }
  __syncthreads();

  int wv = t >> 6;
  int lrow = ln & 15, lk = ln >> 4;
  frag_cd acc[2][4];
  for (int rt = 0; rt < 2; ++rt) for (int ct = 0; ct < 4; ++ct) {
    frag_cd z = {0.f, 0.f, 0.f, 0.f}; acc[rt][ct] = z;
  }
  for (int s = 0; s < 3; ++s) {
    frag_ab a0 = *(const frag_ab*)&A[(wv*32 + lrow) * AS1 + s*32 + lk*8];
    frag_ab a1 = *(const frag_ab*)&A[(wv*32 + 16 + lrow) * AS1 + s*32 + lk*8];
    for (int ct = 0; ct < 4; ++ct) {
      acc[0][ct] = __builtin_amdgcn_mfma_f32_16x16x32_bf16(a0, bf[s*4+ct], acc[0][ct], 0, 0, 0);
      acc[1][ct] = __builtin_amdgcn_mfma_f32_16x16x32_bf16(a1, bf[s*4+ct], acc[1][ct], 0, 0, 0);
    }
  }
  float bv[4];
  for (int ct = 0; ct < 4; ++ct) bv[ct] = bias[ct*16 + lrow];

  __syncthreads();   // A dead; M aliases it
  for (int rt = 0; rt < 2; ++rt)
    for (int ct = 0; ct < 4; ++ct)
      for (int r = 0; r < 4; ++r) {
        int row = wv*32 + rt*16 + lk*4 + r;
        float m = acc[rt][ct][r] + bv[ct];
        m = m > 0.f ? m : 0.1f * m;              // LeakyReLU(0.1)
        M[row * MS + ct*16 + lrow] = m;
      }
  __syncthreads();

  // segment masks via ballot: em bit i = row lo+i ends its dst-run in-window;
  // cm = em minus lowest set bit (run may span from prev window) minus bit31.
  {
    int lo = wv * 32;
    bool end = false;
    if (ln < 32) {
      int di = dstl[lo + ln];
      end = (ln == 31) || (di != dstl[lo + ln + 1]);
    }
    unsigned long long bm = __ballot(end);
    unsigned em = (unsigned)bm;
    unsigned cm = em & ~(em & (0u - em)) & 0x7fffffffu;

    float s = 0.f;
#pragma unroll
    for (int i = 0; i < 32; ++i) {
      s += M[(lo + i) * MS + ln];
      if ((em >> i) & 1u) {
        int d = __builtin_amdgcn_readfirstlane(dstl[lo + i]);
        if (d >= 0) {
          float* dest = &agg[(size_t)d * 64 + ln];
          if ((cm >> i) & 1u) *dest = s;
          else unsafeAtomicAdd(dest, s);
        }
        s = 0.f;
      }
    }
  }
}

// ---------------------------------------------------------------------------
// update: h = [hbf | agg] @ u1_w + b.  K=128 exact. B frags from global.
// Zeroes agg rows after staging (next layer's msg needs zeroed base) — each
// row touched by exactly one thread of one block, race-free.
// fp32 output written only on last layer.
// ---------------------------------------------------------------------------
#define AS2 136   // 272 B row stride, 16B-aligned chunks
__global__ __launch_bounds__(256, 4) void upd_kernel(
    const short* __restrict__ hbf, float* __restrict__ agg,
    const short* __restrict__ wt, const float* __restrict__ bias,
    float* __restrict__ hout, short* __restrict__ hbfo, int N, int last)
{
  __shared__ __align__(16) short A[128 * AS2];
  int t = threadIdx.x;
  int nb = blockIdx.x * 128;
  int ln = t & 63;
  for (int i = 0; i < 4; ++i) {                  // h half (bf16 copy)
    int q = i * 256 + t; int el = q >> 3; int c = q & 7;
    int rg = nb + el;
    uint4 v = {0u, 0u, 0u, 0u};
    if (rg < N) v = *(const uint4*)&hbf[(size_t)rg * 64 + c * 8];
    *(uint4*)&A[el * AS2 + c * 8] = v;
  }
  for (int i = 0; i < 8; ++i) {                  // agg half fp32->bf16 (+zero)
    int q = i * 256 + t; int el = q >> 4; int c = q & 15;
    int rg = nb + el;
    float4 v = make_float4(0.f, 0.f, 0.f, 0.f);
    if (rg < N) {
      v = *(const float4*)&agg[(size_t)rg * 64 + c * 4];
      if (!last) {
        float4 z = make_float4(0.f, 0.f, 0.f, 0.f);
        *(float4*)&agg[(size_t)rg * 64 + c * 4] = z;
      }
    }
    short4v s4 = { f2bf(v.x), f2bf(v.y), f2bf(v.z), f2bf(v.w) };
    *(short4v*)&A[el * AS2 + 64 + c * 4] = s4;
  }
  __syncthreads();
  int wv = t >> 6;
  int lrow = ln & 15, lk = ln >> 4;
  frag_cd acc[2][4];
  for (int rt = 0; rt < 2; ++rt) for (int ct = 0; ct < 4; ++ct) {
    frag_cd z = {0.f, 0.f, 0.f, 0.f}; acc[rt][ct] = z;
  }
  for (int s = 0; s < 4; ++s) {
    frag_ab a0 = *(const frag_ab*)&A[(wv*32 + lrow) * AS2 + s*32 + lk*8];
    frag_ab a1 = *(const frag_ab*)&A[(wv*32 + 16 + lrow) * AS2 + s*32 + lk*8];
    for (int ct = 0; ct < 4; ++ct) {
      frag_ab b = *(const frag_ab*)&wt[((size_t)(s * 4 + ct) * 64 + ln) * 8];
      acc[0][ct] = __builtin_amdgcn_mfma_f32_16x16x32_bf16(a0, b, acc[0][ct], 0, 0, 0);
      acc[1][ct] = __builtin_amdgcn_mfma_f32_16x16x32_bf16(a1, b, acc[1][ct], 0, 0, 0);
    }
  }
  float bv[4];
  for (int ct = 0; ct < 4; ++ct) bv[ct] = bias[ct*16 + lrow];
  for (int rt = 0; rt < 2; ++rt)
    for (int ct = 0; ct < 4; ++ct)
      for (int r = 0; r < 4; ++r) {
        int row = wv*32 + rt*16 + lk*4 + r;
        int rg = nb + row;
        if (rg < N) {
          float v = acc[rt][ct][r] + bv[ct];
          if (last) hout[(size_t)rg * 64 + ct*16 + lrow] = v;
          hbfo[(size_t)rg * 64 + ct*16 + lrow] = f2bf(v);
        }
      }
}

extern "C" void kernel_launch(void* const* d_in, const int* in_sizes, int n_in,
                              void* d_out, int out_size, void* d_ws, size_t ws_size,
                              hipStream_t stream) {
  const float* x    = (const float*)d_in[0];
  const int*   ei   = (const int*)d_in[1];
  const float* attr = (const float*)d_in[2];
  const float* pw   = (const float*)d_in[3];
  const float* pb   = (const float*)d_in[4];
  const float* u2w  = (const float*)d_in[5];
  const float* u2b  = (const float*)d_in[6];
  const float* u1w  = (const float*)d_in[7];
  const float* u1b  = (const float*)d_in[8];

  const int N = in_sizes[0] / 75;
  const int E = in_sizes[1] / 2;
  const int* src = ei;
  const int* dst = ei + E;

  float* hout = (float*)d_out;
  char*  ws   = (char*)d_ws;
  size_t nh   = (size_t)N * 64;
  size_t off  = 0;
  short* hbf   = (short*)(ws + off); off += nh * 2;              // 12.8 MB
  float* agg   = (float*)(ws + off); off += nh * 4;              // 25.6 MB
  int2*  sd    = (int2*) (ws + off); off += (size_t)E * 8;       // 12.8 MB
  short* attr_s= (short*)(ws + off); off += (size_t)E * 32;      // 51.2 MB
  short* projt = (short*)(ws + off); off += 3 * 4 * 64 * 8 * 2;
  short* u2t   = (short*)(ws + off); off += (size_t)3 * 3 * 4 * 64 * 8 * 2;
  short* u1t   = (short*)(ws + off); off += (size_t)3 * 4 * 4 * 64 * 8 * 2;
  // sort scratch overlays agg (dead until msg):
  int* counts  = (int*)agg;
  int* offsets = counts + N;
  int* bsum    = offsets + N;

  const int NB = (N + 127) / 128;
  const int EB = (E + 127) / 128;
  const int GE = (E + 255) / 256;
  const int NS = (N + SCAN_TILE - 1) / SCAN_TILE;

  // one-time preprocessing
  wconv<<<3, 256, 0, stream>>>(pw, projt, 75, 3, 1);
  wconv<<<9, 256, 0, stream>>>(u2w, u2t, 80, 3, 3);
  wconv<<<12, 256, 0, stream>>>(u1w, u1t, 128, 4, 3);
  proj_kernel<<<NB, 256, 0, stream>>>(x, projt, pb, hbf, N);
  hipMemsetAsync(counts, 0, (size_t)N * 4, stream);
  hist_kernel<<<GE, 256, 0, stream>>>(dst, counts, E);
  scan_k1<<<NS, 256, 0, stream>>>(counts, offsets, bsum, N);
  scan_k2<<<1, 64, 0, stream>>>(bsum, NS);
  scan_k3<<<NS, 256, 0, stream>>>(offsets, bsum, N);
  scatter_kernel<<<GE, 256, 0, stream>>>(src, dst, attr, offsets, sd, attr_s, E);

  hipMemsetAsync(agg, 0, nh * 4, stream);       // layer-0 base; upd re-zeros after
  for (int l = 0; l < 3; ++l) {
    msg_kernel<<<EB, 256, 0, stream>>>(hbf, attr_s, sd,
                                       u2t + (size_t)l * 6144, u2b + l * 64,
                                       agg, E);
    upd_kernel<<<NB, 256, 0, stream>>>(hbf, agg,
                                       u1t + (size_t)l * 8192, u1b + l * 64,
                                       hout, hbf, N, l == 2);
  }
}

// Round 7
// 695.950 us; speedup vs baseline: 1.1878x; 1.0106x over previous
//
#include <hip/hip_runtime.h>

typedef __attribute__((ext_vector_type(8))) short frag_ab;   // 8 bf16 = 4 VGPRs
typedef __attribute__((ext_vector_type(4))) float frag_cd;   // 4 fp32 acc

__device__ __forceinline__ short f2bf(float f) {
  union { float f; unsigned u; } v; v.f = f;
  unsigned r = v.u + 0x7fffu + ((v.u >> 16) & 1u);   // RNE
  return (short)(r >> 16);
}

// ---------------------------------------------------------------------------
// wconv: fp32 weights [nmat][Keff][64] -> MFMA B-fragment-ordered bf16:
// frag (s*4+ct), lane ln, elem j = W[k=s*32+(ln>>4)*8+j][n=ct*16+(ln&15)],
// zero-padded k >= Keff. Run once; GEMMs load B frags as single 16B loads.
// ---------------------------------------------------------------------------
__global__ void wconv(const float* __restrict__ W, short* __restrict__ out,
                      int Keff, int S, int nmat)
{
  int tid = blockIdx.x * 256 + threadIdx.x;
  int per = S * 4 * 64;
  if (tid >= nmat * per) return;
  int m = tid / per, r = tid % per;
  int s = r / 256, ct = (r >> 6) & 3, ln = r & 63;
  const float* Wm = W + (size_t)m * Keff * 64;
  __align__(16) short tmp[8];
  for (int j = 0; j < 8; ++j) {
    int k = s * 32 + (ln >> 4) * 8 + j;
    int n = ct * 16 + (ln & 15);
    tmp[j] = (k < Keff) ? f2bf(Wm[k * 64 + n]) : (short)0;
  }
  *(uint4*)&out[((size_t)m * per + (size_t)(s * 4 + ct) * 64 + ln) * 8] = *(uint4*)tmp;
}

// ---------------------------------------------------------------------------
// proj: hbf = bf16(x @ pw + pb).  One-time; LDS-staged A (x rows are fp32,
// 75-wide, unaligned — LDS path is simplest correct).
// ---------------------------------------------------------------------------
#define AS1 104
__global__ __launch_bounds__(256, 4) void proj_kernel(
    const float* __restrict__ x, const short* __restrict__ wt,
    const float* __restrict__ bias, short* __restrict__ hbf, int N)
{
  __shared__ __align__(16) short A[128 * AS1];
  int t = threadIdx.x;
  int nb = blockIdx.x * 128;
  int ln = t & 63;
  frag_ab bf[12];
  for (int s = 0; s < 3; ++s)
    for (int ct = 0; ct < 4; ++ct)
      bf[s * 4 + ct] = *(const frag_ab*)&wt[((size_t)(s * 4 + ct) * 64 + ln) * 8];
  for (int i = 0; i < 48; ++i) {                 // 128*96/256
    int q = i * 256 + t; int el = q / 96; int c = q - el * 96;
    int rg = nb + el;
    float v = (c < 75 && rg < N) ? x[rg * 75 + c] : 0.f;
    A[el * AS1 + c] = f2bf(v);
  }
  __syncthreads();
  int wv = t >> 6;
  int lrow = ln & 15, lk = ln >> 4;
  frag_cd acc[2][4];
  for (int rt = 0; rt < 2; ++rt) for (int ct = 0; ct < 4; ++ct) {
    frag_cd z = {0.f, 0.f, 0.f, 0.f}; acc[rt][ct] = z;
  }
  for (int s = 0; s < 3; ++s) {
    frag_ab a0 = *(const frag_ab*)&A[(wv*32 + lrow) * AS1 + s*32 + lk*8];
    frag_ab a1 = *(const frag_ab*)&A[(wv*32 + 16 + lrow) * AS1 + s*32 + lk*8];
    for (int ct = 0; ct < 4; ++ct) {
      acc[0][ct] = __builtin_amdgcn_mfma_f32_16x16x32_bf16(a0, bf[s*4+ct], acc[0][ct], 0, 0, 0);
      acc[1][ct] = __builtin_amdgcn_mfma_f32_16x16x32_bf16(a1, bf[s*4+ct], acc[1][ct], 0, 0, 0);
    }
  }
  float bv[4];
  for (int ct = 0; ct < 4; ++ct) bv[ct] = bias[ct*16 + lrow];
  for (int rt = 0; rt < 2; ++rt)
    for (int ct = 0; ct < 4; ++ct)
      for (int r = 0; r < 4; ++r) {
        int row = wv*32 + rt*16 + lk*4 + r;
        int rg = nb + row;
        if (rg < N) hbf[(size_t)rg * 64 + ct*16 + lrow] = f2bf(acc[rt][ct][r] + bv[ct]);
      }
}

// ---------------------------------------------------------------------------
// Counting sort by dst. hist captures each edge's rank among its dst (the
// atomic's return), so scatter needs NO atomic: p = offsets[d] + rank[e].
// ---------------------------------------------------------------------------
__global__ __launch_bounds__(256) void hist_kernel(
    const int* __restrict__ dst, int* __restrict__ counts,
    int* __restrict__ rank, int E)
{
  int i = blockIdx.x * 256 + threadIdx.x;
  if (i < E) rank[i] = atomicAdd(&counts[dst[i]], 1);
}

#define SCAN_TILE 2048
__global__ __launch_bounds__(256) void scan_k1(
    const int* __restrict__ counts, int* __restrict__ offsets,
    int* __restrict__ bsum, int n)
{
  __shared__ int ts[256];
  int t = threadIdx.x;
  int base = blockIdx.x * SCAN_TILE + t * 8;
  int v[8]; int s = 0;
  for (int j = 0; j < 8; ++j) { v[j] = (base + j < n) ? counts[base + j] : 0; s += v[j]; }
  ts[t] = s; __syncthreads();
  for (int off = 1; off < 256; off <<= 1) {
    int x = (t >= off) ? ts[t - off] : 0;
    __syncthreads();
    ts[t] += x;
    __syncthreads();
  }
  if (t == 255) bsum[blockIdx.x] = ts[255];
  int run = (t > 0) ? ts[t - 1] : 0;
  for (int j = 0; j < 8; ++j) { if (base + j < n) offsets[base + j] = run; run += v[j]; }
}

// one-wave shfl exclusive scan (nb <= 64)
__global__ void scan_k2(int* bsum, int nb) {
  int ln = threadIdx.x;
  int v = (ln < nb) ? bsum[ln] : 0;
  int x = v;
  for (int off = 1; off < 64; off <<= 1) {
    int y = __shfl_up(x, off);
    if (ln >= off) x += y;
  }
  if (ln < nb) bsum[ln] = x - v;
}

__global__ __launch_bounds__(256) void scan_k3(
    int* __restrict__ offsets, const int* __restrict__ bsum, int n)
{
  int add = bsum[blockIdx.x];
  int base = blockIdx.x * SCAN_TILE + threadIdx.x;
  for (int j = 0; j < 8; ++j) { int i = base + j * 256; if (i < n) offsets[i] += add; }
}

// atomic-free scatter: pure loads + scattered stores, deep pipelining
__global__ __launch_bounds__(256) void scatter_kernel(
    const int* __restrict__ src, const int* __restrict__ dst,
    const float* __restrict__ attr, const int* __restrict__ offsets,
    const int* __restrict__ rank, int2* __restrict__ sd,
    short* __restrict__ attr_s, int E)
{
  int e = blockIdx.x * 256 + threadIdx.x;
  if (e < E) {
    int d = dst[e];
    int p = offsets[d] + rank[e];
    sd[p] = make_int2(src[e], d);
    const float4* a4 = (const float4*)(attr + (size_t)e * 16);
    float4 v0 = a4[0], v1 = a4[1], v2 = a4[2], v3 = a4[3];
    __align__(16) short tmp[16];
    tmp[0]=f2bf(v0.x); tmp[1]=f2bf(v0.y); tmp[2]=f2bf(v0.z); tmp[3]=f2bf(v0.w);
    tmp[4]=f2bf(v1.x); tmp[5]=f2bf(v1.y); tmp[6]=f2bf(v1.z); tmp[7]=f2bf(v1.w);
    tmp[8]=f2bf(v2.x); tmp[9]=f2bf(v2.y); tmp[10]=f2bf(v2.z); tmp[11]=f2bf(v2.w);
    tmp[12]=f2bf(v3.x); tmp[13]=f2bf(v3.y); tmp[14]=f2bf(v3.z); tmp[15]=f2bf(v3.w);
    *(uint4*)&attr_s[(size_t)p * 16]     = *(uint4*)&tmp[0];
    *(uint4*)&attr_s[(size_t)p * 16 + 8] = *(uint4*)&tmp[8];
  }
}

// ---------------------------------------------------------------------------
// msg v4: A-fragments loaded DIRECTLY from global (no A-LDS): lane (lrow,lk),
// step s reads hbf[src*64 + s*32 + lk*8] (s<2) / attr_s[p*16 + lk*8] (s=2,
// lk<2; else zero — B is zero-padded there too). LDS only for M + dstl.
// Segment masks via ballot; interior runs plain-store, boundary runs atomic.
// agg must be zeroed before launch.
// ---------------------------------------------------------------------------
#define MS 66
__global__ __launch_bounds__(256, 4) void msg_kernel(
    const short* __restrict__ hbf, const short* __restrict__ attr_s,
    const int2* __restrict__ sd, const short* __restrict__ wt,
    const float* __restrict__ bias, float* __restrict__ agg, int E)
{
  __shared__ float M[128 * MS];                  // 33792 B
  __shared__ int dstl[128];
  int t = threadIdx.x;
  int eb = blockIdx.x * 128;
  int ln = t & 63;
  int wv = t >> 6;
  int lrow = ln & 15, lk = ln >> 4;

  if (t < 128) dstl[t] = (eb + t < E) ? sd[eb + t].y : -1;

  int p0 = eb + wv*32 + lrow;  if (p0 > E - 1) p0 = E - 1;
  int p1 = p0 + 16;            if (p1 > E - 1) p1 = E - 1;
  int s0 = sd[p0].x, s1 = sd[p1].x;

  frag_ab a[3][2];
  a[0][0] = *(const frag_ab*)&hbf[(size_t)s0 * 64 + lk*8];
  a[0][1] = *(const frag_ab*)&hbf[(size_t)s1 * 64 + lk*8];
  a[1][0] = *(const frag_ab*)&hbf[(size_t)s0 * 64 + 32 + lk*8];
  a[1][1] = *(const frag_ab*)&hbf[(size_t)s1 * 64 + 32 + lk*8];
  frag_ab z8 = {0,0,0,0,0,0,0,0};
  a[2][0] = (lk < 2) ? *(const frag_ab*)&attr_s[(size_t)p0 * 16 + lk*8] : z8;
  a[2][1] = (lk < 2) ? *(const frag_ab*)&attr_s[(size_t)p1 * 16 + lk*8] : z8;

  frag_cd acc[2][4];
  for (int rt = 0; rt < 2; ++rt) for (int ct = 0; ct < 4; ++ct) {
    frag_cd z = {0.f, 0.f, 0.f, 0.f}; acc[rt][ct] = z;
  }
  for (int s = 0; s < 3; ++s)
    for (int ct = 0; ct < 4; ++ct) {
      frag_ab b = *(const frag_ab*)&wt[((size_t)(s * 4 + ct) * 64 + ln) * 8];
      acc[0][ct] = __builtin_amdgcn_mfma_f32_16x16x32_bf16(a[s][0], b, acc[0][ct], 0, 0, 0);
      acc[1][ct] = __builtin_amdgcn_mfma_f32_16x16x32_bf16(a[s][1], b, acc[1][ct], 0, 0, 0);
    }
  float bv[4];
  for (int ct = 0; ct < 4; ++ct) bv[ct] = bias[ct*16 + lrow];

  for (int rt = 0; rt < 2; ++rt)
    for (int ct = 0; ct < 4; ++ct)
      for (int r = 0; r < 4; ++r) {
        int row = wv*32 + rt*16 + lk*4 + r;
        float m = acc[rt][ct][r] + bv[ct];
        m = m > 0.f ? m : 0.1f * m;              // LeakyReLU(0.1)
        M[row * MS + ct*16 + lrow] = m;
      }
  __syncthreads();

  // segmented reduction: wave wv owns rows [wv*32, wv*32+32), lane ln owns col ln.
  {
    int lo = wv * 32;
    bool end = false;
    if (ln < 32) {
      int di = dstl[lo + ln];
      end = (ln == 31) || (di != dstl[lo + ln + 1]);
    }
    unsigned long long bm = __ballot(end);
    unsigned em = (unsigned)bm;
    unsigned cm = em & ~(em & (0u - em)) & 0x7fffffffu;

    float s = 0.f;
#pragma unroll
    for (int i = 0; i < 32; ++i) {
      s += M[(lo + i) * MS + ln];
      if ((em >> i) & 1u) {
        int d = __builtin_amdgcn_readfirstlane(dstl[lo + i]);
        if (d >= 0) {
          float* dest = &agg[(size_t)d * 64 + ln];
          if ((cm >> i) & 1u) *dest = s;
          else unsafeAtomicAdd(dest, s);
        }
        s = 0.f;
      }
    }
  }
}

// ---------------------------------------------------------------------------
// upd v2: no LDS. A-frags direct from global: s<2 -> hbf rows, s>=2 -> agg
// (fp32->bf16 in-reg) with fused re-zeroing (each (row,col-octet) owned by
// exactly one lane; tail rows neither load nor zero). In-place hbf safe:
// each wave reads/writes only its own 32-row window; stores follow MFMA
// consumption of loads.
// ---------------------------------------------------------------------------
__global__ __launch_bounds__(256, 4) void upd_kernel(
    const short* __restrict__ hbf, float* __restrict__ agg,
    const short* __restrict__ wt, const float* __restrict__ bias,
    float* __restrict__ hout, short* __restrict__ hbfo, int N, int last)
{
  int t = threadIdx.x;
  int nb = blockIdx.x * 128;
  int ln = t & 63;
  int wv = t >> 6;
  int lrow = ln & 15, lk = ln >> 4;
  int r0 = nb + wv*32 + lrow;
  int r1 = r0 + 16;

  frag_ab z8 = {0,0,0,0,0,0,0,0};
  frag_ab a[4][2];
  a[0][0] = (r0 < N) ? *(const frag_ab*)&hbf[(size_t)r0 * 64 + lk*8]      : z8;
  a[0][1] = (r1 < N) ? *(const frag_ab*)&hbf[(size_t)r1 * 64 + lk*8]      : z8;
  a[1][0] = (r0 < N) ? *(const frag_ab*)&hbf[(size_t)r0 * 64 + 32 + lk*8] : z8;
  a[1][1] = (r1 < N) ? *(const frag_ab*)&hbf[(size_t)r1 * 64 + 32 + lk*8] : z8;
  for (int si = 0; si < 2; ++si) {
    int cb = si * 32 + lk * 8;                   // agg col base
    for (int rt = 0; rt < 2; ++rt) {
      int rg = rt ? r1 : r0;
      frag_ab af = z8;
      if (rg < N) {
        float* ap = &agg[(size_t)rg * 64 + cb];
        float4 v0 = *(const float4*)ap;
        float4 v1 = *(const float4*)(ap + 4);
        af[0]=f2bf(v0.x); af[1]=f2bf(v0.y); af[2]=f2bf(v0.z); af[3]=f2bf(v0.w);
        af[4]=f2bf(v1.x); af[5]=f2bf(v1.y); af[6]=f2bf(v1.z); af[7]=f2bf(v1.w);
        if (!last) {
          float4 z = make_float4(0.f, 0.f, 0.f, 0.f);
          *(float4*)ap = z; *(float4*)(ap + 4) = z;
        }
      }
      a[2 + si][rt] = af;
    }
  }

  frag_cd acc[2][4];
  for (int rt = 0; rt < 2; ++rt) for (int ct = 0; ct < 4; ++ct) {
    frag_cd z = {0.f, 0.f, 0.f, 0.f}; acc[rt][ct] = z;
  }
  for (int s = 0; s < 4; ++s)
    for (int ct = 0; ct < 4; ++ct) {
      frag_ab b = *(const frag_ab*)&wt[((size_t)(s * 4 + ct) * 64 + ln) * 8];
      acc[0][ct] = __builtin_amdgcn_mfma_f32_16x16x32_bf16(a[s][0], b, acc[0][ct], 0, 0, 0);
      acc[1][ct] = __builtin_amdgcn_mfma_f32_16x16x32_bf16(a[s][1], b, acc[1][ct], 0, 0, 0);
    }
  float bv[4];
  for (int ct = 0; ct < 4; ++ct) bv[ct] = bias[ct*16 + lrow];
  for (int rt = 0; rt < 2; ++rt)
    for (int ct = 0; ct < 4; ++ct)
      for (int r = 0; r < 4; ++r) {
        int row = wv*32 + rt*16 + lk*4 + r;
        int rg = nb + row;
        if (rg < N) {
          float v = acc[rt][ct][r] + bv[ct];
          if (last) hout[(size_t)rg * 64 + ct*16 + lrow] = v;
          hbfo[(size_t)rg * 64 + ct*16 + lrow] = f2bf(v);
        }
      }
}

extern "C" void kernel_launch(void* const* d_in, const int* in_sizes, int n_in,
                              void* d_out, int out_size, void* d_ws, size_t ws_size,
                              hipStream_t stream) {
  const float* x    = (const float*)d_in[0];
  const int*   ei   = (const int*)d_in[1];
  const float* attr = (const float*)d_in[2];
  const float* pw   = (const float*)d_in[3];
  const float* pb   = (const float*)d_in[4];
  const float* u2w  = (const float*)d_in[5];
  const float* u2b  = (const float*)d_in[6];
  const float* u1w  = (const float*)d_in[7];
  const float* u1b  = (const float*)d_in[8];

  const int N = in_sizes[0] / 75;
  const int E = in_sizes[1] / 2;
  const int* src = ei;
  const int* dst = ei + E;

  float* hout = (float*)d_out;
  char*  ws   = (char*)d_ws;
  size_t nh   = (size_t)N * 64;
  size_t off  = 0;
  short* hbf   = (short*)(ws + off); off += nh * 2;              // 12.8 MB
  float* agg   = (float*)(ws + off); off += nh * 4;              // 25.6 MB
  int2*  sd    = (int2*) (ws + off); off += (size_t)E * 8;       // 12.8 MB
  short* attr_s= (short*)(ws + off); off += (size_t)E * 32;      // 51.2 MB
  int*   rank  = (int*)  (ws + off); off += (size_t)E * 4;       //  6.4 MB
  short* projt = (short*)(ws + off); off += 3 * 4 * 64 * 8 * 2;
  short* u2t   = (short*)(ws + off); off += (size_t)3 * 3 * 4 * 64 * 8 * 2;
  short* u1t   = (short*)(ws + off); off += (size_t)3 * 4 * 4 * 64 * 8 * 2;
  // sort scratch overlays agg (dead until msg):
  int* counts  = (int*)agg;
  int* offsets = counts + N;
  int* bsum    = offsets + N;

  const int NB = (N + 127) / 128;
  const int EB = (E + 127) / 128;
  const int GE = (E + 255) / 256;
  const int NS = (N + SCAN_TILE - 1) / SCAN_TILE;

  // one-time preprocessing
  wconv<<<3, 256, 0, stream>>>(pw, projt, 75, 3, 1);
  wconv<<<9, 256, 0, stream>>>(u2w, u2t, 80, 3, 3);
  wconv<<<12, 256, 0, stream>>>(u1w, u1t, 128, 4, 3);
  proj_kernel<<<NB, 256, 0, stream>>>(x, projt, pb, hbf, N);
  hipMemsetAsync(counts, 0, (size_t)N * 4, stream);
  hist_kernel<<<GE, 256, 0, stream>>>(dst, counts, rank, E);
  scan_k1<<<NS, 256, 0, stream>>>(counts, offsets, bsum, N);
  scan_k2<<<1, 64, 0, stream>>>(bsum, NS);
  scan_k3<<<NS, 256, 0, stream>>>(offsets, bsum, N);
  scatter_kernel<<<GE, 256, 0, stream>>>(src, dst, attr, offsets, rank,
                                         sd, attr_s, E);

  hipMemsetAsync(agg, 0, nh * 4, stream);       // layer-0 base; upd re-zeros after
  for (int l = 0; l < 3; ++l) {
    msg_kernel<<<EB, 256, 0, stream>>>(hbf, attr_s, sd,
                                       u2t + (size_t)l * 6144, u2b + l * 64,
                                       agg, E);
    upd_kernel<<<NB, 256, 0, stream>>>(hbf, agg,
                                       u1t + (size_t)l * 8192, u1b + l * 64,
                                       hout, hbf, N, l == 2);
  }
}